// Round 2
// baseline (618.956 us; speedup 1.0000x reference)
//
#include <hip/hip_runtime.h>

// Problem constants (from reference)
#define BB 8
#define CC 64
#define TT 50
#define HH 64
#define WW 64
#define HO 32
#define WO 32
#define PLANE (HH * WW)            // 4096 floats per (b,c,t) plane
#define BC_STRIDE (TT * PLANE)     // 204800 floats per (b,c)
#define OUT_T_STRIDE (HO * WO)     // 1024
#define OUT_BC_STRIDE (TT * OUT_T_STRIDE)  // 51200
#define N_OUT_MAIN (BB * CC * OUT_BC_STRIDE)  // 26214400 (loss scalar follows)

// One block handles half of one (b,c) plane-stack:
//   rows [r*32, r*32+32) of the 64x64 plane, for all T timesteps.
// Grid = 8*64*2 = 1024 blocks of 256 threads (4 blocks/CU, 16 waves/CU).
__global__ __launch_bounds__(256)
void spike_pool_kernel(const float* __restrict__ x, float* __restrict__ out) {
    const int blk = blockIdx.x;     // 0..1023
    const int bc  = blk >> 1;       // 0..511  (b*64 + c)
    const int r   = blk & 1;        // which half of the plane (rows r*32 .. r*32+31)
    const int tid = threadIdx.x;    // 0..255

    const float* xbc = x + (size_t)bc * BC_STRIDE + r * 2048;  // half-plane offset

    // ---- Pass 1: weighted temporal sum, replicating np fp32 rounding ----
    // Reference: x_sum = np.cumsum(x, axis=2).sum(axis=2), both sequential
    // fp32 ops (cumsum is sequential by definition; sum over a non-innermost
    // axis is sequential plane accumulation in numpy). We keep the running
    // cumsum c and the running sum-of-cumsums s in fp32, updated in the same
    // order -> bit-identical x_sum -> identical argmax (first-max semantics).
    float c[8], s[8];
#pragma unroll
    for (int k = 0; k < 8; ++k) { c[k] = 0.0f; s[k] = 0.0f; }

    for (int t = 0; t < TT; ++t) {
        const float4* p = (const float4*)(xbc + (size_t)t * PLANE);
        float4 v0 = p[tid];         // floats [4*tid, 4*tid+4)   of half-plane
        float4 v1 = p[256 + tid];   // floats [1024+4*tid, ...)
        c[0] += v0.x; s[0] += c[0];
        c[1] += v0.y; s[1] += c[1];
        c[2] += v0.z; s[2] += c[2];
        c[3] += v0.w; s[3] += c[3];
        c[4] += v1.x; s[4] += c[4];
        c[5] += v1.y; s[5] += c[5];
        c[6] += v1.z; s[6] += c[6];
        c[7] += v1.w; s[7] += c[7];
    }

    // Stage the half-plane weighted sum (2048 floats = 8 KiB LDS).
    __shared__ float xs[2048];
#pragma unroll
    for (int k = 0; k < 4; ++k) xs[4 * tid + k] = s[k];
#pragma unroll
    for (int k = 0; k < 4; ++k) xs[1024 + 4 * tid + k] = s[4 + k];
    __syncthreads();

    // ---- Argmax over each 2x2 window (first-max semantics) --------------
    // Half-plane has 16x32 = 512 windows; thread handles windows 2*tid, 2*tid+1.
    // Candidate order matches reference flat order: a, a+1, a+W, a+W+1.
    int widx[2];
#pragma unroll
    for (int q = 0; q < 2; ++q) {
        const int wi = 2 * tid + q;          // local window id, 0..511
        const int lho = wi >> 5;             // 0..15
        const int wo  = wi & 31;             // 0..31
        const int a = (lho * 2) * WW + wo * 2;  // local flat of top-left candidate
        const float v0 = xs[a];
        const float v1 = xs[a + 1];
        const float v2 = xs[a + WW];
        const float v3 = xs[a + WW + 1];
        int best = a;
        float bv = v0;
        if (v1 > bv) { bv = v1; best = a + 1; }
        if (v2 > bv) { bv = v2; best = a + WW; }
        if (v3 > bv) { bv = v3; best = a + WW + 1; }
        widx[q] = best + r * 2048;           // global flat index within full plane
    }

    // ---- Pass 2: gather winner at every timestep ------------------------
    // Reverse t order: the t-slices streamed most recently by pass 1 across
    // all blocks (~30 slices = 252 MB) may still be L3-resident.
    const float* xp = x + (size_t)bc * BC_STRIDE;
    float* obc = out + (size_t)bc * OUT_BC_STRIDE + r * 512;
    for (int t = TT - 1; t >= 0; --t) {
        const float* plane = xp + (size_t)t * PLANE;
        float2 o;
        o.x = plane[widx[0]];
        o.y = plane[widx[1]];
        ((float2*)(obc + (size_t)t * OUT_T_STRIDE))[tid] = o;
    }

    // Scalar loss output (= 0.0f), appended after spk_rec.
    if (blk == 0 && tid == 0) out[N_OUT_MAIN] = 0.0f;
}

extern "C" void kernel_launch(void* const* d_in, const int* in_sizes, int n_in,
                              void* d_out, int out_size, void* d_ws, size_t ws_size,
                              hipStream_t stream) {
    const float* x = (const float*)d_in[0];
    float* out = (float*)d_out;
    dim3 grid(BB * CC * 2);
    dim3 block(256);
    spike_pool_kernel<<<grid, block, 0, stream>>>(x, out);
}